// Round 9
// baseline (74.959 us; speedup 1.0000x reference)
//
#include <hip/hip_runtime.h>
#include <math.h>

// Problem constants (match reference)
#define NF 256          // features
#define NB 64           // batch
#define M_CON 515       // 2N+3 constraints
static constexpr double EPS_Q  = 1e-4;
static constexpr double SIGMA  = 0.1;
static constexpr double CAPC   = 10.0;
static constexpr int    ITERS  = 20;

// Fast fp64 reciprocal: v_rcp_f64 seed + 1 NR step -> ~fp64 noise floor.
// Used for everything feeding the Newton direction.
__device__ __forceinline__ double drcp(double x) {
    double r = __builtin_amdgcn_rcp(x);
    r = fma(r, fma(-x, r, 1.0), r);
    return r;
}

// DPP cross-lane fp64 (two 32-bit movs) and fp32 (one mov). VALU-speed.
template <int CTRL>
__device__ __forceinline__ double dpp_d(double v) {
    const int lo = __builtin_amdgcn_update_dpp(0, __double2loint(v), CTRL, 0xF, 0xF, true);
    const int hi = __builtin_amdgcn_update_dpp(0, __double2hiint(v), CTRL, 0xF, 0xF, true);
    return __hiloint2double(hi, lo);
}
template <int CTRL>
__device__ __forceinline__ float dpp_f(float v) {
    return __int_as_float(
        __builtin_amdgcn_update_dpp(0, __float_as_int(v), CTRL, 0xF, 0xF, true));
}
__device__ __forceinline__ double bcast63(double v) {
    const int lo = __builtin_amdgcn_readlane(__double2loint(v), 63);
    const int hi = __builtin_amdgcn_readlane(__double2hiint(v), 63);
    return __hiloint2double(hi, lo);
}
__device__ __forceinline__ float bcast63f(float v) {
    return __int_as_float(__builtin_amdgcn_readlane(__float_as_int(v), 63));
}
// Wave64 sum: row_ror 1/2/4/8 rotation-butterfly, then row_bcast15/31
// (bound_ctrl=1 injects 0); lane 63 holds the total.
__device__ __forceinline__ double wave_red_sum(double v) {
    v += dpp_d<0x121>(v);
    v += dpp_d<0x122>(v);
    v += dpp_d<0x124>(v);
    v += dpp_d<0x128>(v);
    v += dpp_d<0x142>(v);
    v += dpp_d<0x143>(v);
    return bcast63(v);
}
// fp32 max of nonnegative values (0-injection safe).
__device__ __forceinline__ float wave_red_maxf_nn(float v) {
    v = fmaxf(v, dpp_f<0x121>(v));
    v = fmaxf(v, dpp_f<0x122>(v));
    v = fmaxf(v, dpp_f<0x124>(v));
    v = fmaxf(v, dpp_f<0x128>(v));
    v = fmaxf(v, dpp_f<0x142>(v));
    v = fmaxf(v, dpp_f<0x143>(v));
    return bcast63f(v);
}

// One wave per batch item (R7: multi-wave split is latency-neutral).
// Lane j owns features j, j+64, j+128, j+192.
// Constraints: row0: sum(x)<=C ; lo_i: -x_i<=0 ; hi_i: x_i<=1 ;
// rowA: m.x <= rhs_fair+1 ; rowB: -m.x <= -rhs_fair.
//
// Exact-identity fp64 formulation (trajectory == the 2.06e-7 R4 kernel):
//  * rhs = e - G^T phi, phi_r = d_r rs_r + smu/s_r; scalar-row shift
//    w = phi0 + (phiA-phiB)*m folded into Nr -> C1=c1, C2=c2 direct.
//  * rs scales by (1-alpha); musum' = musum(1-a+a*sigma)+a^2*Sum(ds.dz).
//  * single-rcp y/invD: denom = EPS*sl*sh + zl*sh + zh*sl (all-positive).
//  * Sdx/Smdx via identities (no reduction).
//  * Step ratios/alpha in fp32 (step-length-only, 1e-7-class perturbation,
//    benign per R5-R8); Sdsdz reduce stays fp64, overlaps fp32 rmax reduce.
//  * Capacitance: deferred-NR (corr = 2-den*r applied to final products).
__global__ __launch_bounds__(64)
void pdipm_kernel(const float* __restrict__ xin,
                  const int* __restrict__ male,
                  float* __restrict__ out) {
    const int b = blockIdx.x;
    const int lane = threadIdx.x;

    double e[4], x[4];                        // e = -(EPS*x + p) tracked
    bool mb[4];
    double s_lo[4], s_hi[4], z_lo[4], z_hi[4];
    double rs_lo[4], rs_hi[4];
    double msum_p = 0.0;
    #pragma unroll
    for (int k = 0; k < 4; ++k) {
        const int f = lane + 64 * k;
        e[k]  = (double)xin[b * NF + f];       // e = -p = xin at x=0
        const int m = male[f];
        mb[k] = (m != 0);
        msum_p += (double)m;
        x[k] = 0.0;
        s_lo[k] = 1.0; s_hi[k] = 1.0;
        z_lo[k] = 1.0; z_hi[k] = 1.0;
        rs_lo[k] = 1.0;                        // s - x
        rs_hi[k] = 0.0;                        // s + x - 1
    }
    const double nm = wave_red_sum(msum_p);
    const double rhs_fair = CAPC * nm * (1.0 / 256.0);

    // Scalar-constraint state (wave-uniform).
    double s0 = 1.0, z0 = 1.0, sA = 1.0, zA = 1.0, sB = 1.0, zB = 1.0;
    double rs0 = 1.0 - CAPC;
    double rsA = -rhs_fair;
    double rsB = 1.0 + rhs_fair;
    double musum = (double)M_CON;

    for (int it = 0; it < ITERS; ++it) {
        const double smu = SIGMA * musum * (1.0 / (double)M_CON);

        // ---- uniform scalar precompute ----
        const double i_s0 = drcp(s0), i_sA = drcp(sA), i_sB = drcp(sB);
        const double d0 = z0 * i_s0, dA = zA * i_sA, dB = zB * i_sB;
        const double beta  = d0 * rs0 + smu * i_s0;                 // phi0
        const double gamma = (dA * rsA + smu * i_sA) - (dB * rsB + smu * i_sB);
        const double bpg = beta + gamma;
        const double ia  = drcp(d0);
        const double ibb = drcp(dA + dB);
        const double g0 = fma(smu, i_s0, -z0);
        const double gA = fma(smu, i_sA, -zA);
        const double gB = fma(smu, i_sB, -zB);

        // ---- group 1: single-rcp y/invD with scalar-row shift folded ----
        double invD[4], y[4], i_sl[4], i_sh[4];
        double dl[4], dh[4], gl[4], gh[4];
        #pragma unroll
        for (int k = 0; k < 4; ++k) {
            const double prod  = s_lo[k] * s_hi[k];
            const double denom = fma(EPS_Q, prod,
                                     fma(z_lo[k], s_hi[k], z_hi[k] * s_lo[k]));
            const double R = drcp(denom);
            invD[k] = prod * R;
            const double w = mb[k] ? bpg : beta;
            const double Nr0 = fma(e[k], prod,
                               fma(z_lo[k] * rs_lo[k], s_hi[k],
                               fma(-(z_hi[k] * rs_hi[k]), s_lo[k],
                                   smu * (s_hi[k] - s_lo[k]))));
            const double Nr = fma(-w, prod, Nr0);
            y[k] = Nr * R;
            // off-path (consumed post-reduce; hides under DPP latency)
            i_sl[k] = drcp(s_lo[k]);
            i_sh[k] = drcp(s_hi[k]);
            dl[k] = z_lo[k] * i_sl[k];
            dh[k] = z_hi[k] * i_sh[k];
            gl[k] = fma(smu, i_sl[k], -z_lo[k]);
            gh[k] = fma(smu, i_sh[k], -z_hi[k]);
        }
        const double s11 = wave_red_sum((invD[0] + invD[1]) + (invD[2] + invD[3]));
        const double s12 = wave_red_sum((mb[0] ? invD[0] : 0.0) + (mb[1] ? invD[1] : 0.0)
                                      + ((mb[2] ? invD[2] : 0.0) + (mb[3] ? invD[3] : 0.0)));
        const double t1  = wave_red_sum((y[0] + y[1]) + (y[2] + y[3]));
        const double t2  = wave_red_sum((mb[0] ? y[0] : 0.0) + (mb[1] ? y[1] : 0.0)
                                      + ((mb[2] ? y[2] : 0.0) + (mb[3] ? y[3] : 0.0)));

        // ---- 2x2 capacitance, deferred-NR (corr applied to final C) ----
        const double k11 = ia + s11;
        const double k22 = ibb + s12;
        const double den2 = k11 * k22 - s12 * s12;
        const double r2 = __builtin_amdgcn_rcp(den2);
        const double corr = fma(-den2, r2, 2.0);       // ILP with c1'/c2'
        const double C1 = ((k22 * t1 - s12 * t2) * r2) * corr;
        const double C2 = ((k11 * t2 - s12 * t1) * r2) * corr;
        const double C1pC2 = C1 + C2;

        // ---- Sdx/Smdx via identities; scalar directions ----
        const double Sdx  = t1 - C1 * s11 - C2 * s12;
        const double Smdx = t2 - C1pC2 * s12;
        const double ds0 = -rs0 - Sdx;
        const double dsA = -rsA - Smdx;
        const double dsB = -rsB + Smdx;
        const double dz0 = fma(-d0, ds0, g0);
        const double dzA = fma(-dA, dsA, gA);
        const double dzB = fma(-dB, dsB, gB);

        // ---- group 2: directions; fp64 Sdsdz + fp32 rmax ----
        // scalar ratios (fp32, step-length only)
        float rmax_p = fmaxf(
            fmaxf(fmaxf((float)(-ds0 * i_s0), -(float)dz0 * __builtin_amdgcn_rcpf((float)z0)),
                  fmaxf((float)(-dsA * i_sA), -(float)dzA * __builtin_amdgcn_rcpf((float)zA))),
            fmaxf(fmaxf((float)(-dsB * i_sB), -(float)dzB * __builtin_amdgcn_rcpf((float)zB)),
                  0.0f));
        double dsdz_p = (lane == 0) ? (ds0 * dz0 + dsA * dzA + dsB * dzB) : 0.0;
        double dx[4], ds_l[4], ds_h[4], dz_l[4], dz_h[4];
        #pragma unroll
        for (int k = 0; k < 4; ++k) {
            const double C12 = mb[k] ? C1pC2 : C1;
            dx[k] = fma(-invD[k], C12, y[k]);
            ds_l[k] = dx[k] - rs_lo[k];        // ds = -rs - G dx, (G dx)_lo = -dx
            ds_h[k] = -dx[k] - rs_hi[k];
            dz_l[k] = fma(-dl[k], ds_l[k], gl[k]);
            dz_h[k] = fma(-dh[k], ds_h[k], gh[k]);
            dsdz_p += ds_l[k] * dz_l[k] + ds_h[k] * dz_h[k];
            // fp32 ratio block: z-side uses rcpf (removes fp64 trans ops)
            const float qs = fmaxf((float)(-ds_l[k] * i_sl[k]),
                                   (float)(-ds_h[k] * i_sh[k]));
            const float qzl = -(float)dz_l[k] * __builtin_amdgcn_rcpf((float)z_lo[k]);
            const float qzh = -(float)dz_h[k] * __builtin_amdgcn_rcpf((float)z_hi[k]);
            rmax_p = fmaxf(rmax_p, fmaxf(qs, fmaxf(qzl, qzh)));
        }
        const double Sdsdz = wave_red_sum(dsdz_p);     // overlaps fp32 reduce
        const float  rmax  = wave_red_maxf_nn(rmax_p);

        const float  alphaf = fminf(1.0f, 0.99f * __builtin_amdgcn_rcpf(fmaxf(rmax, 0.99f)));
        const double alpha  = (double)alphaf;
        const double omA = 1.0 - alpha;

        // ---- state update (identities keep rs/musum exact) ----
        #pragma unroll
        for (int k = 0; k < 4; ++k) {
            const double adx = alpha * dx[k];
            x[k] += adx;
            e[k] = fma(-EPS_Q, adx, e[k]);
            s_lo[k] = fma(alpha, ds_l[k], s_lo[k]);
            s_hi[k] = fma(alpha, ds_h[k], s_hi[k]);
            z_lo[k] = fma(alpha, dz_l[k], z_lo[k]);
            z_hi[k] = fma(alpha, dz_h[k], z_hi[k]);
            rs_lo[k] *= omA;
            rs_hi[k] *= omA;
        }
        s0 = fma(alpha, ds0, s0); z0 = fma(alpha, dz0, z0);
        sA = fma(alpha, dsA, sA); zA = fma(alpha, dzA, zA);
        sB = fma(alpha, dsB, sB); zB = fma(alpha, dzB, zB);
        rs0 *= omA; rsA *= omA; rsB *= omA;
        musum = musum * (1.0 - alpha * (1.0 - SIGMA)) + alpha * alpha * Sdsdz;
    }

    #pragma unroll
    for (int k = 0; k < 4; ++k)
        out[b * NF + lane + 64 * k] = (float)x[k];
}

extern "C" void kernel_launch(void* const* d_in, const int* in_sizes, int n_in,
                              void* d_out, int out_size, void* d_ws, size_t ws_size,
                              hipStream_t stream) {
    const float* xin  = (const float*)d_in[0];   // [64, 256] fp32
    const int*   male = (const int*)d_in[1];     // [256] int32
    float* out = (float*)d_out;                  // [64, 256] fp32
    pdipm_kernel<<<NB, 64, 0, stream>>>(xin, male, out);
}